// Round 3
// baseline (1048.340 us; speedup 1.0000x reference)
//
#include <hip/hip_runtime.h>
#include <stdint.h>

// Problem: x[16,3,32,32] f32, images[50000,3,32,32] f32, t scalar.
// score = -(sum_w * x - mu * (w @ img)) / (sigma^2 * sum_w + 1e-8),
// w = exp(-(x2 - 2 mu S + mu^2 i2) / (2 sigma^2)), S = x @ img^T.
// Flash-style single pass over images (614 MB read once -> ~97us HBM floor).
#define DDIM 3072
#define BQ 16
#define NIMG 50000
#define NBLK 256
#define DW 192                 // DDIM / 16 waves
#define IMSTRIDE 416           // bytes per img row in LDS (192 bf16 = 384B + pad)
#define IMREG (16 * IMSTRIDE)  // 6656 B per-wave image region [16 img][192 d] bf16
#define IM_TOT (16 * IMREG)            // 106496
#define SP_OFF IM_TOT                  // S-partials f32[16w][64l][4]  (16384 B)
#define I2P_OFF (SP_OFF + 16 * 64 * 16)  // 122880: i2 partials f32[16w][16img]
#define W_OFF   (I2P_OFF + 16 * 16 * 4)  // 123904: w bf16[16b][16img] (32B rows)
#define SMEM_TOTAL (W_OFF + 512)         // 124416 B (< 160 KiB)

typedef float f32x4 __attribute__((ext_vector_type(4)));
typedef short s16x8 __attribute__((ext_vector_type(8)));

union U8 { struct { uint32_t a, b, c, d; } u; s16x8 v; };

__device__ __forceinline__ uint32_t bfu(float f) {
  union { float f; uint32_t u; } c; c.f = f;
  return (c.u + 0x7fffu + ((c.u >> 16) & 1u)) >> 16;  // RNE f32->bf16
}
__device__ __forceinline__ uint32_t pk2(float a, float b) {
  return bfu(a) | (bfu(b) << 16);
}

// ---------------- K0: schedule constants + x2[b] + zero sumw ----------------
__global__ __launch_bounds__(1024) void k0_setup(const float* __restrict__ x,
                                                 const int* __restrict__ tptr,
                                                 float* __restrict__ cst) {
  const int tid = threadIdx.x;
  const int w = tid >> 6, l = tid & 63;
  if (tid == 0) {
    const int t = tptr[0];
    const float step = (0.02f - 1e-4f) / 999.f;  // jnp.linspace(1e-4, 0.02, 1000)
    float ab = 1.f, abt = 1.f;
    for (int i = 0; i < 1000; ++i) {
      float beta = 1e-4f + step * (float)i;
      ab *= (1.f - beta);
      if (i == t) abt = ab;
    }
    float mu = sqrtf(abt);
    float s2 = 1.f - abt;            // sigma^2
    cst[0] = mu;
    cst[1] = s2;
    cst[2] = 0.5f / s2;              // 1/(2 sigma^2)
    cst[3] = mu * mu;
  }
  // x2[b]: wave w handles row b=w
  const float* xr = x + w * DDIM;
  float acc = 0.f;
  for (int i = l; i < DDIM; i += 64) { float v = xr[i]; acc += v * v; }
  #pragma unroll
  for (int m = 1; m < 64; m <<= 1) acc += __shfl_xor(acc, m, 64);
  if (l == 0) cst[4 + w] = acc;
  if (tid < 16) cst[20 + tid] = 0.f;  // sumw accumulators
}

// ---------------- kz: zero partial buffer (atomic fallback only) ----------------
__global__ void kz_zero(float* __restrict__ p, long long n) {
  long long i = (long long)blockIdx.x * blockDim.x + threadIdx.x;
  long long stride = (long long)gridDim.x * blockDim.x;
  for (; i < n; i += stride) p[i] = 0.f;
}

// ---------------- K1: fused flash-score main kernel ----------------
// 256 blocks x 1024 thr (16 waves). Wave w owns d-slice [w*192, (w+1)*192).
// Per 16-image tile:
//   stage: lane (img=l&15, qs=l>>4) loads 12 float4 (48 d), packs bf16 into
//          LDS im_w[img][d] (img-major), accumulates i2 partial.
//   phase A: S-partial = mfma(xf, im-row). Both fragments use the SAME
//          (g,e)->d formula (d = 32s + 8g + e), so any common HW k-order cancels.
//   wave 0: reduce S + i2 across waves, w = exp(...), store w to LDS (bf16).
//   phase B: acc[b][d] += mfma(wa, gathered im cols); A and B fragments use the
//          SAME (g,e)->img formula (img = 8g+e, valid for g<2, wa=0 for g>=2).
template <bool ATOMIC>
__global__ __launch_bounds__(1024) void k1_main(const float* __restrict__ Xp,
                                                const float* __restrict__ Img,
                                                float* __restrict__ cst,
                                                float* __restrict__ pacc,
                                                int slots) {
  extern __shared__ char smem[];
  const int tid = threadIdx.x;
  const int w = tid >> 6, l = tid & 63;
  const int g = l >> 4, ln16 = l & 15;
  const int img = ln16, qs = g;  // staging aliases

  const float mu = cst[0];
  const float inv2s2 = cst[2];
  const float mu2 = cst[3];
  const f32x4 x2v = *(const f32x4*)(cst + 4 + 4 * g);  // x2[4g..4g+3]

  // xf[s] elem e <-> d = w*192 + 32s + 8g + e (contiguous 8 floats, bf16-packed
  // in memory order -- same order as the phase-A b128 LDS read of im rows).
  s16x8 xf[6];
  {
    const float* xb = Xp + ln16 * DDIM + w * DW + g * 8;
    #pragma unroll
    for (int s = 0; s < 6; ++s) {
      f32x4 lo = *(const f32x4*)(xb + s * 32);
      f32x4 hi = *(const f32x4*)(xb + s * 32 + 4);
      U8 u;
      u.u.a = pk2(lo[0], lo[1]); u.u.b = pk2(lo[2], lo[3]);
      u.u.c = pk2(hi[0], hi[1]); u.u.d = pk2(hi[2], hi[3]);
      xf[s] = u.v;
    }
  }

  f32x4 acc[12];
  #pragma unroll
  for (int i = 0; i < 12; ++i) acc[i] = (f32x4){0.f, 0.f, 0.f, 0.f};
  f32x4 swacc = (f32x4){0.f, 0.f, 0.f, 0.f};  // wave 0: running sum_w[4g+r]

  const int n0 = (int)(((long long)blockIdx.x * NIMG) >> 8);
  const int n1 = (int)(((long long)(blockIdx.x + 1) * NIMG) >> 8);

  const uint32_t wbase = (uint32_t)(w * IMREG + img * IMSTRIDE + qs * 96);
  const uint32_t rbase = (uint32_t)(w * IMREG + ln16 * IMSTRIDE);

  for (int tb = n0; tb < n1; tb += 16) {
    // ---- staging (wave-private region; same-wave LDS ops are in-order) ----
    const bool valid = (tb + img) < n1;
    const float* gsrc = Img + (size_t)(tb + img) * DDIM + w * DW + qs * 48;
    float i2 = 0.f;
    #pragma unroll
    for (int h = 0; h < 2; ++h) {   // two halves of 6 float4 (VGPR cap 128)
      f32x4 v[6];
      #pragma unroll
      for (int it = 0; it < 6; ++it)
        v[it] = valid ? *(const f32x4*)(gsrc + h * 24 + it * 4)
                      : (f32x4){0.f, 0.f, 0.f, 0.f};
      #pragma unroll
      for (int it = 0; it < 6; ++it) {
        i2 += v[it][0] * v[it][0]; i2 += v[it][1] * v[it][1];
        i2 += v[it][2] * v[it][2]; i2 += v[it][3] * v[it][3];
        uint64_t p = (uint64_t)pk2(v[it][0], v[it][1])
                   | ((uint64_t)pk2(v[it][2], v[it][3]) << 32);
        *(uint64_t*)(smem + wbase + h * 48 + it * 8) = p;  // d-ascending bf16
      }
    }
    // i2 partial over this wave's 192 d: reduce across qs (lanes +16, +32)
    i2 += __shfl_xor(i2, 16, 64);
    i2 += __shfl_xor(i2, 32, 64);
    if (qs == 0) *(float*)(smem + I2P_OFF + (w * 16 + img) * 4) = i2;

    // ---- phase A: S-partial over this wave's d-slice ----
    f32x4 sf = (f32x4){0.f, 0.f, 0.f, 0.f};
    #pragma unroll
    for (int s = 0; s < 6; ++s) {
      s16x8 bb = *(const s16x8*)(smem + rbase + 64 * s + 16 * g);  // img=ln16, d=32s+8g+e
      sf = __builtin_amdgcn_mfma_f32_16x16x32_bf16(xf[s], bb, sf, 0, 0, 0);
    }
    *(f32x4*)(smem + SP_OFF + w * 1024 + l * 16) = sf;  // (l,r) = S[4g+r][ln16]

    __syncthreads();

    // ---- wave 0: reduce S across waves, compute w = exp(...) ----
    if (w == 0) {
      f32x4 s = (f32x4){0.f, 0.f, 0.f, 0.f};
      #pragma unroll
      for (int ww = 0; ww < 16; ++ww)
        s += *(const f32x4*)(smem + SP_OFF + ww * 1024 + l * 16);
      float i2n = 0.f;
      #pragma unroll
      for (int ww = 0; ww < 16; ++ww)
        i2n += *(const float*)(smem + I2P_OFF + ww * 64 + ln16 * 4);
      const bool v16 = (tb + ln16) < n1;
      f32x4 wv;
      #pragma unroll
      for (int r = 0; r < 4; ++r) {
        // exponent = -(x2 - 2 mu S + mu^2 i2)/(2 sigma^2); underflows to 0 like ref
        float e = (2.f * mu * s[r] - x2v[r] - mu2 * i2n) * inv2s2;
        wv[r] = v16 ? __expf(e) : 0.f;
      }
      swacc += wv;
      #pragma unroll
      for (int r = 0; r < 4; ++r)
        *(uint16_t*)(smem + W_OFF + (4 * g + r) * 32 + ln16 * 2) = (uint16_t)bfu(wv[r]);
    }

    __syncthreads();

    // ---- phase B: acc[b][d] += sum_img w[b][img] * im[img][d] ----
    // A fragment: elem (g,e) = w[b=ln16][8g+e] for g<2, 0 for g>=2.
    s16x8 wa;
    { U8 z; z.u.a = 0; z.u.b = 0; z.u.c = 0; z.u.d = 0; wa = z.v; }
    if (g < 2) wa = *(const s16x8*)(smem + W_OFF + ln16 * 32 + g * 16);
    #pragma unroll
    for (int sub = 0; sub < 12; ++sub) {
      const uint32_t gb2 = (uint32_t)(w * IMREG + (sub * 16 + ln16) * 2);
      uint32_t r[8];
      #pragma unroll
      for (int e = 0; e < 8; ++e) {
        const int m = 8 * (g & 1) + e;  // == (8g+e)&15 (g>=2 pairs with wa=0)
        r[e] = *(const uint16_t*)(smem + gb2 + m * IMSTRIDE);
      }
      U8 bb;
      bb.u.a = r[0] | (r[1] << 16); bb.u.b = r[2] | (r[3] << 16);
      bb.u.c = r[4] | (r[5] << 16); bb.u.d = r[6] | (r[7] << 16);
      acc[sub] = __builtin_amdgcn_mfma_f32_16x16x32_bf16(wa, bb.v, acc[sub], 0, 0, 0);
    }
    // next staging overwrites only own-wave im region (same-wave in-order);
    // cross-wave SP/I2P/W hazards are ordered by the two barriers above.
  }

  // ---- writeout: partial acc -> slot, sum_w -> atomics ----
  float* slot = pacc + (size_t)(ATOMIC ? (int)(blockIdx.x % slots) : (int)blockIdx.x) * (BQ * DDIM);
  #pragma unroll
  for (int sub = 0; sub < 12; ++sub) {
    #pragma unroll
    for (int r = 0; r < 4; ++r) {
      int b = 4 * g + r;
      int d = w * DW + sub * 16 + ln16;
      if (ATOMIC) atomicAdd(slot + b * DDIM + d, acc[sub][r]);
      else slot[b * DDIM + d] = acc[sub][r];
    }
  }
  if (w == 0) {
    #pragma unroll
    for (int m = 1; m <= 8; m <<= 1) {
      #pragma unroll
      for (int r = 0; r < 4; ++r) swacc[r] += __shfl_xor(swacc[r], m, 64);
    }
    if (ln16 == 0) {
      #pragma unroll
      for (int r = 0; r < 4; ++r) atomicAdd(cst + 20 + 4 * g + r, swacc[r]);
    }
  }
}

// ---------------- K3: reduce partials + final score ----------------
__global__ __launch_bounds__(256) void k3_fin(const float* __restrict__ ws,
                                              const float* __restrict__ x,
                                              const float* __restrict__ pacc,
                                              float* __restrict__ out,
                                              int slots) {
  int idx = blockIdx.x * 256 + threadIdx.x;  // 0..49151
  float mu = ws[0], s2 = ws[1];
  int b = idx / DDIM;
  float sw = ws[20 + b];
  float a = 0.f;
  for (int k = 0; k < slots; ++k) a += pacc[(size_t)k * (BQ * DDIM) + idx];
  float xv = x[idx];
  out[idx] = -(sw * xv - mu * a) / (s2 * sw + 1e-8f);
}

extern "C" void kernel_launch(void* const* d_in, const int* in_sizes, int n_in,
                              void* d_out, int out_size, void* d_ws, size_t ws_size,
                              hipStream_t stream) {
  const float* X = (const float*)d_in[0];
  const float* Img = (const float*)d_in[1];
  const int* T = (const int*)d_in[2];
  float* out = (float*)d_out;
  float* ws = (float*)d_ws;
  float* pacc = ws + 64;

  // slot budget: primary = 256 private slots (50.3 MB); fallback = fewer + atomics
  const size_t need = ((size_t)64 + (size_t)NBLK * BQ * DDIM) * 4;
  int slots = NBLK;
  bool atomic = false;
  if (ws_size < need) {
    size_t avail = (ws_size / 4 > 64) ? (ws_size / 4 - 64) : 0;
    slots = (int)(avail / (BQ * DDIM));
    if (slots < 1) slots = 1;
    if (slots > NBLK) slots = NBLK;
    atomic = true;
  }

  hipFuncSetAttribute(reinterpret_cast<const void*>(&k1_main<false>),
                      hipFuncAttributeMaxDynamicSharedMemorySize, SMEM_TOTAL);
  hipFuncSetAttribute(reinterpret_cast<const void*>(&k1_main<true>),
                      hipFuncAttributeMaxDynamicSharedMemorySize, SMEM_TOTAL);

  k0_setup<<<1, 1024, 0, stream>>>(X, T, ws);
  if (atomic) {
    kz_zero<<<512, 256, 0, stream>>>(pacc, (long long)slots * BQ * DDIM);
    k1_main<true><<<NBLK, 1024, SMEM_TOTAL, stream>>>(X, Img, ws, pacc, slots);
  } else {
    k1_main<false><<<NBLK, 1024, SMEM_TOTAL, stream>>>(X, Img, ws, pacc, slots);
  }
  k3_fin<<<192, 256, 0, stream>>>(ws, X, pacc, out, slots);
}